// Round 5
// baseline (21.660 us; speedup 1.0000x reference)
//
#include <hip/hip_runtime.h>

// DendSN: dendritic spiking neuron forward.
// x_seq: (T=8, N=16, C=128, H=32, W=32) fp32 ; k: (1,4,1) fp32
// out:   (T=8, N=16, K=32, H=32, W=32) fp32 (0/1 spikes)
//
// R5: ONE THREAD PER SITE. 524288 threads = 32 waves/CU grid (full), zero
// redundant compute, every lane stores every t (dense full-wave contiguous
// stores), loads = 4 scalar dwords/thread at 4KiB stride (each a contiguous
// 256B wave transaction). Removes R4's 4x LIF redundancy + partial-wave
// stores while keeping max occupancy. ~25 VGPR.

#define TT 8
#define NB 16
#define CC 128
#define BB 4
#define KK 32
#define LL 1024   // H*W

__global__ __launch_bounds__(256, 8) void dendsn_fwd(
    const float* __restrict__ x, const float* __restrict__ k,
    float* __restrict__ out)
{
    const int site = blockIdx.x * 256 + threadIdx.x;   // [0, 524288)
    const int l  = site & 1023;
    const int kk = (site >> 10) & 31;
    const int n  = site >> 15;

    // softmax over the 4 dendritic-strength params, folded with the *3.0
    const float k0 = k[0], k1 = k[1], k2 = k[2], k3 = k[3];
    const float m  = fmaxf(fmaxf(k0, k1), fmaxf(k2, k3));
    const float e0 = expf(k0 - m), e1 = expf(k1 - m),
                e2 = expf(k2 - m), e3 = expf(k3 - m);
    const float inv_s = 1.0f / (e0 + e1 + e2 + e3);
    const float fs[4] = { 3.0f * e0 * inv_s, 3.0f * e1 * inv_s,
                          3.0f * e2 * inv_s, 3.0f * e3 * inv_s };

    // mexican hat constants
    const float v     = 0.75f + 1e-5f;
    const float inv_v = 1.0f / v;
    const float gs    = 1.0f / sqrtf(2.0f * 3.14159265358979323846f * v);

    const size_t tstride_x = (size_t)NB * CC * LL;     // 2M elements
    const size_t tstride_o = (size_t)NB * KK * LL;     // 512K elements
    const size_t base_x = ((size_t)n * CC + (size_t)kk * BB) * LL + l;
    const size_t base_o = ((size_t)n * KK + kk) * LL + l;

    float pre[4];   // dendritic filter state, one per compartment
    float h = 0.0f; // somatic LIF state
    #pragma unroll
    for (int b = 0; b < 4; ++b) pre[b] = 0.0f;

    // depth-1 named prefetch
    float xv[4], xn[4];
    #pragma unroll
    for (int b = 0; b < 4; ++b) xv[b] = x[base_x + (size_t)b * LL];

    #pragma unroll
    for (int t = 0; t < TT; ++t) {
        if (t + 1 < TT) {
            const size_t bx = base_x + (size_t)(t + 1) * tstride_x;
            #pragma unroll
            for (int b = 0; b < 4; ++b) xn[b] = x[bx + (size_t)b * LL];
        }

        float y = 0.0f;
        #pragma unroll
        for (int b = 0; b < 4; ++b) {
            const float p = 0.5f * pre[b] + xv[b];      // alpha decay
            pre[b] = p;
            const float q = p * p * inv_v;
            const float g = expf(-0.5f * q) * gs;       // gaussian
            y += fs[b] * ((1.0f - q) * g * inv_v);      // weighted mexican hat
        }

        const float hh = 0.5f * h + y;                  // beta decay
        const float s  = (hh - 1.0f >= 0.0f) ? 1.0f : 0.0f;  // heaviside
        h = (s != 0.0f) ? 0.0f : hh;                    // hard reset
        out[base_o + (size_t)t * tstride_o] = s;

        #pragma unroll
        for (int b = 0; b < 4; ++b) xv[b] = xn[b];
    }
}

extern "C" void kernel_launch(void* const* d_in, const int* in_sizes, int n_in,
                              void* d_out, int out_size, void* d_ws, size_t ws_size,
                              hipStream_t stream)
{
    const float* x = (const float*)d_in[0];
    const float* k = (const float*)d_in[1];
    float* out = (float*)d_out;

    // one thread per site: 16*32*1024 = 524288 threads -> 2048 blocks of 256
    dendsn_fwd<<<2048, 256, 0, stream>>>(x, k, out);
}